// Round 5
// baseline (447.656 us; speedup 1.0000x reference)
//
#include <hip/hip_runtime.h>
#include <hip/hip_fp16.h>

#define BB 2
#define DX 160
#define DY 160
#define DZ 160

constexpr int    VOL        = DX * DY * DZ;          // 4,096,000
constexpr int    NVOX       = BB * VOL;              // 8,192,000
constexpr size_t PACK_BYTES = (size_t)NVOX * 16;     // 131,072,000 B
constexpr int    HZ         = DZ / 2;                // 80 float4 (z-pairs) per column
constexpr int    QZ         = DZ / 4;                // 40 z-quads per column

typedef float f2v __attribute__((ext_vector_type(2)));
typedef float f4v __attribute__((ext_vector_type(4)));

// ---------------------------------------------------------------------------
// Pack: for each (b,x,y,z) store the XY-QUAD at that z (4 corners x 2ch fp16
// = 16 B), quads contiguous along z (identical layout to rounds 2-4).
//
// Round-5: NON-TEMPORAL pk stores. Read-side tiling (r3/r4) proved neutral;
// the untested invariant is the store path: 131 MB of cached write-allocates
// churning the 4 MiB L2s, evicting the im rows whose reuse we need. nt stores
// skip L2 allocation (gather is insensitive to pk caching: r1 pk>L3 ran at
// the same rate as r2 pk<L3). Each thread packs a z-QUAD (4 voxels): 4 rows x
// 32 B reads, one aligned 64 B contiguous nt store.
// ---------------------------------------------------------------------------
constexpr int TBX = 4, TBY = 8, TBZ = 8;             // 4*8*8 = 256 threads
constexpr int NBX = DX / TBX;                        // 40
constexpr int NBY = DY / TBY;                        // 20
constexpr int NBZ = QZ / TBZ;                        // 5
constexpr int PACK_BLOCKS = BB * NBX * NBY * NBZ;    // 8000 (divisible by 8)

__global__ __launch_bounds__(256) void pack_kernel(const float* __restrict__ im,
                                                   float4* __restrict__ pk)
{
    // chunked XCD swizzle (bijective: nblk % 8 == 0)
    const int nblk  = gridDim.x;                     // 8000
    const int chunk = nblk >> 3;
    const int bid   = blockIdx.x;
    int t = (bid & 7) * chunk + (bid >> 3);

    const int bz = t % NBZ; t /= NBZ;
    const int by = t % NBY; t /= NBY;
    const int bx = t % NBX; t /= NBX;
    const int b  = t;

    const int tid = threadIdx.x;
    const int tz  = tid & 7;
    const int ty  = (tid >> 3) & 7;
    const int tx  = tid >> 6;

    const int x  = bx * TBX + tx;
    const int y  = by * TBY + ty;
    const int zq = bz * TBZ + tz;                    // z-quad: voxels 4zq..4zq+3

    const int x1 = min(x + 1, DX - 1);
    const int y1 = min(y + 1, DY - 1);

    // two float4 per row = voxels (4zq..4zq+3) x 2ch
    const float4* __restrict__ imf4 = (const float4*)im;
    const int r00 = ((b * DX + x ) * DY + y ) * HZ + zq * 2;
    const int r01 = ((b * DX + x ) * DY + y1) * HZ + zq * 2;
    const int r10 = ((b * DX + x1) * DY + y ) * HZ + zq * 2;
    const int r11 = ((b * DX + x1) * DY + y1) * HZ + zq * 2;

    const float4 a00 = imf4[r00], b00 = imf4[r00 + 1];
    const float4 a01 = imf4[r01], b01 = imf4[r01 + 1];
    const float4 a10 = imf4[r10], b10 = imf4[r10 + 1];
    const float4 a11 = imf4[r11], b11 = imf4[r11 + 1];

    // quad k (voxel z = 4zq+k): corners (0,0),(0,1),(1,0),(1,1)
    __half2 q[4][4];
    q[0][0] = __floats2half2_rn(a00.x, a00.y);
    q[0][1] = __floats2half2_rn(a01.x, a01.y);
    q[0][2] = __floats2half2_rn(a10.x, a10.y);
    q[0][3] = __floats2half2_rn(a11.x, a11.y);
    q[1][0] = __floats2half2_rn(a00.z, a00.w);
    q[1][1] = __floats2half2_rn(a01.z, a01.w);
    q[1][2] = __floats2half2_rn(a10.z, a10.w);
    q[1][3] = __floats2half2_rn(a11.z, a11.w);
    q[2][0] = __floats2half2_rn(b00.x, b00.y);
    q[2][1] = __floats2half2_rn(b01.x, b01.y);
    q[2][2] = __floats2half2_rn(b10.x, b10.y);
    q[2][3] = __floats2half2_rn(b11.x, b11.y);
    q[3][0] = __floats2half2_rn(b00.z, b00.w);
    q[3][1] = __floats2half2_rn(b01.z, b01.w);
    q[3][2] = __floats2half2_rn(b10.z, b10.w);
    q[3][3] = __floats2half2_rn(b11.z, b11.w);

    // one aligned 64 B contiguous run of 4 nt stores
    const size_t qbase = (size_t)((b * DX + x) * DY + y) * DZ + 4 * zq;
    f4v* dst = (f4v*)(pk + qbase);
#pragma unroll
    for (int k = 0; k < 4; ++k)
        __builtin_nontemporal_store(*(const f4v*)&q[k][0], dst + k);
}

// ---------------------------------------------------------------------------
// Gather (round-2 version — best measured, UNCHANGED): two adjacent 16B quad
// reads per voxel, trilinear in fp32, 4 voxels/thread. Pinned at ~3.3 TB/s
// random-line fabric rate; defgrid/out non-temporal streams.
// ---------------------------------------------------------------------------
__device__ __forceinline__ void lerp_quads(const float4 Q0, const float4 Q1,
                                           float fx, float fy, float fz,
                                           float& rx, float& ry)
{
    union { float4 f4; __half2 h2[4]; } a, b;
    a.f4 = Q0;
    b.f4 = Q1;

    const float wx[2] = { 1.0f - fx, fx };
    const float wy[2] = { 1.0f - fy, fy };

    rx = 0.0f; ry = 0.0f;
#pragma unroll
    for (int c = 0; c < 4; ++c) {
        const float w = wx[(c >> 1) & 1] * wy[c & 1];
        const float2 v0 = __half22float2(a.h2[c]);
        const float2 v1 = __half22float2(b.h2[c]);
        rx += w * (v0.x + fz * (v1.x - v0.x));
        ry += w * (v0.y + fz * (v1.y - v0.y));
    }
}

__global__ __launch_bounds__(256) void gather_kernel(const float4* __restrict__ pk,
                                                     const float* __restrict__ defgrid,
                                                     float2* __restrict__ out)
{
    constexpr int Q = NVOX / 4;  // 2,048,000
    const int t = blockIdx.x * blockDim.x + threadIdx.x;
    if (t >= Q) return;

    int   idx[4];
    float xf[4], yf[4], zf[4];
#pragma unroll
    for (int k = 0; k < 4; ++k) {
        idx[k] = t + k * Q;
        const float* g = defgrid + (size_t)idx[k] * 3;
        xf[k] = __builtin_nontemporal_load(g + 0);
        yf[k] = __builtin_nontemporal_load(g + 1);
        zf[k] = __builtin_nontemporal_load(g + 2);
    }

    size_t q0[4], q1[4];
    float  fx[4], fy[4], fz[4];
#pragma unroll
    for (int k = 0; k < 4; ++k) {
        const int ax = min(max((int)floorf(xf[k]), 0), DX - 1);
        const int ay = min(max((int)floorf(yf[k]), 0), DY - 1);
        const int az = min(max((int)floorf(zf[k]), 0), DZ - 1);
        const int z1 = min(az + 1, DZ - 1);
        const int b  = (idx[k] >= VOL) ? 1 : 0;
        const size_t base = (size_t)(((b * DX + ax) * DY + ay)) * DZ;
        q0[k] = base + az;
        q1[k] = base + z1;
        fx[k] = xf[k] - (float)ax;
        fy[k] = yf[k] - (float)ay;
        fz[k] = zf[k] - (float)az;
    }

    // issue all 8 quad loads before consuming
    float4 A[4], B[4];
#pragma unroll
    for (int k = 0; k < 4; ++k) {
        A[k] = pk[q0[k]];
        B[k] = pk[q1[k]];
    }

#pragma unroll
    for (int k = 0; k < 4; ++k) {
        float rx, ry;
        lerp_quads(A[k], B[k], fx[k], fy[k], fz[k], rx, ry);
        f2v r;
        r.x = rx;
        r.y = ry;
        __builtin_nontemporal_store(r, (f2v*)(out + idx[k]));
    }
}

// ---------------------------------------------------------------------------
// Fallback direct kernel in case ws_size < PACK_BYTES.
// ---------------------------------------------------------------------------
__global__ __launch_bounds__(256) void trilerp3d_direct(
    const float* __restrict__ im,
    const float* __restrict__ defgrid,
    float*       __restrict__ out)
{
    int idx = blockIdx.x * blockDim.x + threadIdx.x;
    if (idx >= NVOX) return;

    const float x = defgrid[(size_t)idx * 3 + 0];
    const float y = defgrid[(size_t)idx * 3 + 1];
    const float z = defgrid[(size_t)idx * 3 + 2];

    const int x0u = (int)floorf(x);
    const int y0u = (int)floorf(y);
    const int z0u = (int)floorf(z);

    const int x0 = min(max(x0u, 0), DX - 1);
    const int x1 = min(max(x0u + 1, 0), DX - 1);
    const int y0 = min(max(y0u, 0), DY - 1);
    const int y1 = min(max(y0u + 1, 0), DY - 1);
    const int z0 = min(max(z0u, 0), DZ - 1);
    const int z1 = min(max(z0u + 1, 0), DZ - 1);

    const float xd = x - (float)x0;
    const float yd = y - (float)y0;
    const float zd = z - (float)z0;

    const int b    = idx / VOL;
    const int base = b * VOL;

    const float2* __restrict__ imf = (const float2*)im;

    const int px0 = base + x0 * (DY * DZ);
    const int px1 = base + x1 * (DY * DZ);
    const int oy0 = y0 * DZ;
    const int oy1 = y1 * DZ;

    const float2 Ia = imf[px0 + oy0 + z0];
    const float2 Ib = imf[px0 + oy0 + z1];
    const float2 Ic = imf[px0 + oy1 + z0];
    const float2 Id = imf[px0 + oy1 + z1];
    const float2 Ie = imf[px1 + oy0 + z0];
    const float2 If = imf[px1 + oy0 + z1];
    const float2 Ig = imf[px1 + oy1 + z0];
    const float2 Ih = imf[px1 + oy1 + z1];

    const float xm = 1.0f - xd, ym = 1.0f - yd, zm = 1.0f - zd;

    float cae_x = Ia.x * xm + Ie.x * xd;
    float cae_y = Ia.y * xm + Ie.y * xd;
    float cbf_x = Ib.x * xm + If.x * xd;
    float cbf_y = Ib.y * xm + If.y * xd;
    float ccg_x = Ic.x * xm + Ig.x * xd;
    float ccg_y = Ic.y * xm + Ig.y * xd;
    float cdh_x = Id.x * xm + Ih.x * xd;
    float cdh_y = Id.y * xm + Ih.y * xd;

    float c0_x = cae_x * ym + ccg_x * yd;
    float c0_y = cae_y * ym + ccg_y * yd;
    float c1_x = cbf_x * ym + cdh_x * yd;
    float c1_y = cbf_y * ym + cdh_y * yd;

    float2 r;
    r.x = c0_x * zm + c1_x * zd;
    r.y = c0_y * zm + c1_y * zd;
    ((float2*)out)[idx] = r;
}

extern "C" void kernel_launch(void* const* d_in, const int* in_sizes, int n_in,
                              void* d_out, int out_size, void* d_ws, size_t ws_size,
                              hipStream_t stream) {
    const float* im      = (const float*)d_in[0];
    const float* defgrid = (const float*)d_in[1];
    float*       out     = (float*)d_out;

    const int block = 256;

    if (ws_size >= PACK_BYTES) {
        float4* pk = (float4*)d_ws;
        pack_kernel<<<PACK_BLOCKS, block, 0, stream>>>(im, pk);
        const int gridG = (NVOX / 4 + block - 1) / block;  // 8000
        gather_kernel<<<gridG, block, 0, stream>>>(pk, defgrid, (float2*)out);
    } else {
        const int grid = (NVOX + block - 1) / block;
        trilerp3d_direct<<<grid, block, 0, stream>>>(im, defgrid, out);
    }
}

// Round 6
// 393.976 us; speedup vs baseline: 1.1363x; 1.1363x over previous
//
#include <hip/hip_runtime.h>
#include <hip/hip_fp16.h>

#define BB 2
#define DX 160
#define DY 160
#define DZ 160

constexpr int    VOL        = DX * DY * DZ;          // 4,096,000
constexpr int    NVOX       = BB * VOL;              // 8,192,000
constexpr size_t PACK_BYTES = (size_t)NVOX * 16;     // 131,072,000 B

typedef float f2v __attribute__((ext_vector_type(2)));

// ---------------------------------------------------------------------------
// Pack (round-2 structure, PROBE: body executed TWICE).
// The rep loop with an opaque pointer + memory clobber forces the compiler to
// keep both copies of loads/converts/stores -> pack dispatch duration = 2P.
// Purpose: surface pack in the rocprof top-5 (cutoff ~184 us) so its true
// per-dispatch time and FETCH/WRITE become directly measurable. If it stays
// hidden, P < ~92 us and the ~185 us residual is harness overhead, not pack.
// ---------------------------------------------------------------------------
__global__ __launch_bounds__(256) void pack_kernel(const float* __restrict__ im,
                                                   float4* __restrict__ pk)
{
    int cell = blockIdx.x * blockDim.x + threadIdx.x;
    if (cell >= NVOX) return;

    int z = cell % DZ;
    int t = cell / DZ;
    int y = t % DY;
    t /= DY;
    int x = t % DX;
    int b = t / DX;

    const int x1 = min(x + 1, DX - 1);
    const int y1 = min(y + 1, DY - 1);

    const int i00 = ((b * DX + x ) * DY + y ) * DZ + z;
    const int i01 = ((b * DX + x ) * DY + y1) * DZ + z;
    const int i10 = ((b * DX + x1) * DY + y ) * DZ + z;
    const int i11 = ((b * DX + x1) * DY + y1) * DZ + z;

    unsigned long long ip = (unsigned long long)(const void*)im;

#pragma unroll 1
    for (int rep = 0; rep < 2; ++rep) {
        const float2* __restrict__ imf = (const float2*)ip;

        const float2 v00 = imf[i00];
        const float2 v01 = imf[i01];
        const float2 v10 = imf[i10];
        const float2 v11 = imf[i11];

        __half2 h[4];
        h[0] = __floats2half2_rn(v00.x, v00.y);  // corner (0,0)
        h[1] = __floats2half2_rn(v01.x, v01.y);  // (0,1)
        h[2] = __floats2half2_rn(v10.x, v10.y);  // (1,0)
        h[3] = __floats2half2_rn(v11.x, v11.y);  // (1,1)

        pk[cell] = *(const float4*)h;

        // opaque: defeats load-CSE across reps and dead-store elimination of
        // the first pk write; zero runtime cost.
        asm volatile("" : "+v"(ip) :: "memory");
    }
}

// ---------------------------------------------------------------------------
// Gather (round-2 version EXACT — best measured): two adjacent 16B quad reads
// per voxel, trilinear in fp32, 4 voxels/thread; defgrid/out non-temporal.
// Serves as the same-run container-speed calibration for the pack probe.
// ---------------------------------------------------------------------------
__device__ __forceinline__ void lerp_quads(const float4 Q0, const float4 Q1,
                                           float fx, float fy, float fz,
                                           float& rx, float& ry)
{
    union { float4 f4; __half2 h2[4]; } a, b;
    a.f4 = Q0;
    b.f4 = Q1;

    const float wx[2] = { 1.0f - fx, fx };
    const float wy[2] = { 1.0f - fy, fy };

    rx = 0.0f; ry = 0.0f;
#pragma unroll
    for (int c = 0; c < 4; ++c) {
        const float w = wx[(c >> 1) & 1] * wy[c & 1];
        const float2 v0 = __half22float2(a.h2[c]);
        const float2 v1 = __half22float2(b.h2[c]);
        rx += w * (v0.x + fz * (v1.x - v0.x));
        ry += w * (v0.y + fz * (v1.y - v0.y));
    }
}

__global__ __launch_bounds__(256) void gather_kernel(const float4* __restrict__ pk,
                                                     const float* __restrict__ defgrid,
                                                     float2* __restrict__ out)
{
    constexpr int Q = NVOX / 4;  // 2,048,000
    const int t = blockIdx.x * blockDim.x + threadIdx.x;
    if (t >= Q) return;

    int   idx[4];
    float xf[4], yf[4], zf[4];
#pragma unroll
    for (int k = 0; k < 4; ++k) {
        idx[k] = t + k * Q;
        const float* g = defgrid + (size_t)idx[k] * 3;
        xf[k] = __builtin_nontemporal_load(g + 0);
        yf[k] = __builtin_nontemporal_load(g + 1);
        zf[k] = __builtin_nontemporal_load(g + 2);
    }

    size_t q0[4], q1[4];
    float  fx[4], fy[4], fz[4];
#pragma unroll
    for (int k = 0; k < 4; ++k) {
        const int ax = min(max((int)floorf(xf[k]), 0), DX - 1);
        const int ay = min(max((int)floorf(yf[k]), 0), DY - 1);
        const int az = min(max((int)floorf(zf[k]), 0), DZ - 1);
        const int z1 = min(az + 1, DZ - 1);
        const int b  = (idx[k] >= VOL) ? 1 : 0;
        const size_t base = (size_t)(((b * DX + ax) * DY + ay)) * DZ;
        q0[k] = base + az;
        q1[k] = base + z1;
        fx[k] = xf[k] - (float)ax;
        fy[k] = yf[k] - (float)ay;
        fz[k] = zf[k] - (float)az;
    }

    // issue all 8 quad loads before consuming
    float4 A[4], B[4];
#pragma unroll
    for (int k = 0; k < 4; ++k) {
        A[k] = pk[q0[k]];
        B[k] = pk[q1[k]];
    }

#pragma unroll
    for (int k = 0; k < 4; ++k) {
        float rx, ry;
        lerp_quads(A[k], B[k], fx[k], fy[k], fz[k], rx, ry);
        f2v r;
        r.x = rx;
        r.y = ry;
        __builtin_nontemporal_store(r, (f2v*)(out + idx[k]));
    }
}

// ---------------------------------------------------------------------------
// Fallback direct kernel in case ws_size < PACK_BYTES.
// ---------------------------------------------------------------------------
__global__ __launch_bounds__(256) void trilerp3d_direct(
    const float* __restrict__ im,
    const float* __restrict__ defgrid,
    float*       __restrict__ out)
{
    int idx = blockIdx.x * blockDim.x + threadIdx.x;
    if (idx >= NVOX) return;

    const float x = defgrid[(size_t)idx * 3 + 0];
    const float y = defgrid[(size_t)idx * 3 + 1];
    const float z = defgrid[(size_t)idx * 3 + 2];

    const int x0u = (int)floorf(x);
    const int y0u = (int)floorf(y);
    const int z0u = (int)floorf(z);

    const int x0 = min(max(x0u, 0), DX - 1);
    const int x1 = min(max(x0u + 1, 0), DX - 1);
    const int y0 = min(max(y0u, 0), DY - 1);
    const int y1 = min(max(y0u + 1, 0), DY - 1);
    const int z0 = min(max(z0u, 0), DZ - 1);
    const int z1 = min(max(z0u + 1, 0), DZ - 1);

    const float xd = x - (float)x0;
    const float yd = y - (float)y0;
    const float zd = z - (float)z0;

    const int b    = idx / VOL;
    const int base = b * VOL;

    const float2* __restrict__ imf = (const float2*)im;

    const int px0 = base + x0 * (DY * DZ);
    const int px1 = base + x1 * (DY * DZ);
    const int oy0 = y0 * DZ;
    const int oy1 = y1 * DZ;

    const float2 Ia = imf[px0 + oy0 + z0];
    const float2 Ib = imf[px0 + oy0 + z1];
    const float2 Ic = imf[px0 + oy1 + z0];
    const float2 Id = imf[px0 + oy1 + z1];
    const float2 Ie = imf[px1 + oy0 + z0];
    const float2 If = imf[px1 + oy0 + z1];
    const float2 Ig = imf[px1 + oy1 + z0];
    const float2 Ih = imf[px1 + oy1 + z1];

    const float xm = 1.0f - xd, ym = 1.0f - yd, zm = 1.0f - zd;

    float cae_x = Ia.x * xm + Ie.x * xd;
    float cae_y = Ia.y * xm + Ie.y * xd;
    float cbf_x = Ib.x * xm + If.x * xd;
    float cbf_y = Ib.y * xm + If.y * xd;
    float ccg_x = Ic.x * xm + Ig.x * xd;
    float ccg_y = Ic.y * xm + Ig.y * xd;
    float cdh_x = Id.x * xm + Ih.x * xd;
    float cdh_y = Id.y * xm + Ih.y * xd;

    float c0_x = cae_x * ym + ccg_x * yd;
    float c0_y = cae_y * ym + ccg_y * yd;
    float c1_x = cbf_x * ym + cdh_x * yd;
    float c1_y = cbf_y * ym + cdh_y * yd;

    float2 r;
    r.x = c0_x * zm + c1_x * zd;
    r.y = c0_y * zm + c1_y * zd;
    ((float2*)out)[idx] = r;
}

extern "C" void kernel_launch(void* const* d_in, const int* in_sizes, int n_in,
                              void* d_out, int out_size, void* d_ws, size_t ws_size,
                              hipStream_t stream) {
    const float* im      = (const float*)d_in[0];
    const float* defgrid = (const float*)d_in[1];
    float*       out     = (float*)d_out;

    const int block = 256;

    if (ws_size >= PACK_BYTES) {
        float4* pk = (float4*)d_ws;
        const int gridP = (NVOX + block - 1) / block;      // 32000
        pack_kernel<<<gridP, block, 0, stream>>>(im, pk);
        const int gridG = (NVOX / 4 + block - 1) / block;  // 8000
        gather_kernel<<<gridG, block, 0, stream>>>(pk, defgrid, (float2*)out);
    } else {
        const int grid = (NVOX + block - 1) / block;
        trilerp3d_direct<<<grid, block, 0, stream>>>(im, defgrid, out);
    }
}